// Round 2
// baseline (25234.221 us; speedup 1.0000x reference)
//
#include <hip/hip_runtime.h>
#include <stdint.h>

typedef unsigned short u16;
typedef __attribute__((ext_vector_type(8))) short bf16x8;
typedef __attribute__((ext_vector_type(4))) float f32x4;
typedef __attribute__((ext_vector_type(4))) u16 u16x4;

__device__ __forceinline__ u16 f2bf(float f) {
  union { float f; uint32_t u; } v; v.f = f;
  uint32_t u = v.u;
  uint32_t r = u + 0x7fffu + ((u >> 16) & 1u);
  return (u16)(r >> 16);
}
__device__ __forceinline__ float bf2f(u16 h) {
  union { uint32_t u; float f; } v; v.u = ((uint32_t)h) << 16; return v.f;
}
__device__ __forceinline__ float sigm(float x) { return 1.f / (1.f + __expf(-x)); }
__device__ __forceinline__ float tanhfast(float x) {
  float t = __expf(-2.f * fabsf(x));
  float r = (1.f - t) / (1.f + t);
  return x < 0.f ? -r : r;
}

__global__ __launch_bounds__(256) void k_zero(float* __restrict__ p) {
  p[(size_t)blockIdx.x * 256 + threadIdx.x] = 0.f;
}

// Repack Wih||Whh (fp32) -> bf16 fragment-tiled: [l][jb(120)][k0(120)][g(4)][lane(64)][8]
__global__ __launch_bounds__(256) void k_repB(const float* __restrict__ Wih,
                                              const float* __restrict__ Whh,
                                              u16* __restrict__ dst) {
  int e8 = blockIdx.x * 256 + threadIdx.x;
  if (e8 >= 7372800) return;
  int lane = e8 & 63;
  int t1 = e8 >> 6;
  int g = t1 & 3;
  int t2 = t1 >> 2;
  int k0 = t2 % 120;
  int t3 = t2 / 120;
  int jb = t3 % 120;
  int l = t3 / 120;
  int ln = lane & 15, quad = lane >> 4;
  int n = g * 1920 + jb * 16 + ln;
  const float* src = (k0 < 60)
      ? (Wih + ((size_t)(l * 7680 + n)) * 1920 + k0 * 32 + quad * 8)
      : (Whh + ((size_t)(l * 7680 + n)) * 1920 + (k0 - 60) * 32 + quad * 8);
  float4 a = ((const float4*)src)[0];
  float4 b = ((const float4*)src)[1];
  u16x4 o0, o1;
  o0[0] = f2bf(a.x); o0[1] = f2bf(a.y); o0[2] = f2bf(a.z); o0[3] = f2bf(a.w);
  o1[0] = f2bf(b.x); o1[1] = f2bf(b.y); o1[2] = f2bf(b.z); o1[3] = f2bf(b.w);
  ((u16x4*)(dst + (size_t)e8 * 8))[0] = o0;
  ((u16x4*)(dst + (size_t)e8 * 8))[1] = o1;
}

// Repack W3 (fp32 [1920,1920]) -> [nb(30)][k0(60)][nt(4)][lane(64)][8]
__global__ __launch_bounds__(256) void k_repW3(const float* __restrict__ W3,
                                               u16* __restrict__ dst) {
  int e8 = blockIdx.x * 256 + threadIdx.x;
  if (e8 >= 460800) return;
  int lane = e8 & 63;
  int t1 = e8 >> 6;
  int nt = t1 & 3;
  int t2 = t1 >> 2;
  int k0 = t2 % 60;
  int nb = t2 / 60;
  int ln = lane & 15, quad = lane >> 4;
  int n = nb * 64 + nt * 16 + ln;
  const float* src = W3 + (size_t)n * 1920 + k0 * 32 + quad * 8;
  float4 a = ((const float4*)src)[0];
  float4 b = ((const float4*)src)[1];
  u16x4 o0, o1;
  o0[0] = f2bf(a.x); o0[1] = f2bf(a.y); o0[2] = f2bf(a.z); o0[3] = f2bf(a.w);
  o1[0] = f2bf(b.x); o1[1] = f2bf(b.y); o1[2] = f2bf(b.z); o1[3] = f2bf(b.w);
  ((u16x4*)(dst + (size_t)e8 * 8))[0] = o0;
  ((u16x4*)(dst + (size_t)e8 * 8))[1] = o1;
}

// Rolling-pipeline fragment GEMM: ITERS k-iters (32 k each), depth 5.
template <int ITERS>
__device__ __forceinline__ void gemm_pipe(const char* __restrict__ aw,
                                          const char* __restrict__ bw,
                                          int lane_off, f32x4 acc[4][4]) {
  constexpr int D = 5;
  bf16x8 Af[D][4], Bf[D][4];
#pragma unroll
  for (int p = 0; p < D; ++p) {
#pragma unroll
    for (int mt = 0; mt < 4; ++mt)
      Af[p][mt] = *(const bf16x8*)(aw + p * 4096 + mt * 1024 + lane_off);
#pragma unroll
    for (int nt = 0; nt < 4; ++nt)
      Bf[p][nt] = *(const bf16x8*)(bw + p * 4096 + nt * 1024 + lane_off);
  }
  for (int o = 0; o < (ITERS - D) / D; ++o) {
    const char* ap = aw + (size_t)(o + 1) * (D * 4096);
    const char* bp = bw + (size_t)(o + 1) * (D * 4096);
#pragma unroll
    for (int d = 0; d < D; ++d) {
#pragma unroll
      for (int mt = 0; mt < 4; ++mt)
#pragma unroll
        for (int nt = 0; nt < 4; ++nt)
          acc[mt][nt] = __builtin_amdgcn_mfma_f32_16x16x32_bf16(
              Af[d][mt], Bf[d][nt], acc[mt][nt], 0, 0, 0);
#pragma unroll
      for (int mt = 0; mt < 4; ++mt)
        Af[d][mt] = *(const bf16x8*)(ap + d * 4096 + mt * 1024 + lane_off);
#pragma unroll
      for (int nt = 0; nt < 4; ++nt)
        Bf[d][nt] = *(const bf16x8*)(bp + d * 4096 + nt * 1024 + lane_off);
    }
  }
#pragma unroll
  for (int d = 0; d < D; ++d) {
#pragma unroll
    for (int mt = 0; mt < 4; ++mt)
#pragma unroll
      for (int nt = 0; nt < 4; ++nt)
        acc[mt][nt] = __builtin_amdgcn_mfma_f32_16x16x32_bf16(
            Af[d][mt], Bf[d][nt], acc[mt][nt], 0, 0, 0);
  }
}

// ---------------- persistent-kernel infrastructure ----------------
// Sense-reversing grid barrier via device-scope atomics (G16). Blocks are all
// co-resident: grid=240 <= 256 CUs, 64KB LDS + <=512 VGPR => >=1 block/CU.
__device__ unsigned g_bar_ctr = 0;
__device__ unsigned g_bar_gen = 0;

__device__ __forceinline__ void gridbar() {
  __syncthreads();
  if (threadIdx.x == 0) {
    __threadfence();  // release: make this block's writes agent-visible
    unsigned g = __hip_atomic_load(&g_bar_gen, __ATOMIC_RELAXED,
                                   __HIP_MEMORY_SCOPE_AGENT);
    unsigned arrived = __hip_atomic_fetch_add(&g_bar_ctr, 1u, __ATOMIC_ACQ_REL,
                                              __HIP_MEMORY_SCOPE_AGENT) + 1u;
    if (arrived == gridDim.x) {
      __hip_atomic_store(&g_bar_ctr, 0u, __ATOMIC_RELAXED,
                         __HIP_MEMORY_SCOPE_AGENT);
      __hip_atomic_store(&g_bar_gen, g + 1u, __ATOMIC_RELEASE,
                         __HIP_MEMORY_SCOPE_AGENT);
    } else {
      // relaxed spin (no per-iteration cache inv); acquire via fence below
      while (__hip_atomic_load(&g_bar_gen, __ATOMIC_RELAXED,
                               __HIP_MEMORY_SCOPE_AGENT) == g) {
        __builtin_amdgcn_s_sleep(2);
      }
    }
    __threadfence();  // acquire: invalidate stale caches before next phase
  }
  __syncthreads();
}

// Gates GEMM + fused LSTM cell phase. 240 blocks: jb = bid%120, mh = bid/120
// (both mh of a jb land on the same XCD since 120 % 8 == 0 -> B slice L2-reuse).
__device__ __forceinline__ void gates_phase(
    const u16* __restrict__ Atl, const u16* __restrict__ Brep_l,
    const float* __restrict__ bih_l, const float* __restrict__ bhh_l,
    float* __restrict__ c_l, u16* __restrict__ hA, u16* __restrict__ hB,
    int rd_off, int sB, float (*red)[4][16][64], int bid, int tid) {
  const int w = tid >> 6;
  const int lane = tid & 63;
  const int ln = lane & 15, quad = lane >> 4;
  const int jb = bid % 120;
  const int mh = bid / 120;
  const int lane_off = lane * 16;

  const char* ax = (const char*)Atl + (size_t)mh * 180 * 4096;
  const char* ah = ax + (size_t)rd_off * 4096;
  const char* aw = (w < 2) ? (ax + (size_t)(30 * w) * 4096)
                           : (ah + (size_t)(30 * (w - 2)) * 4096);
  const char* bw = (const char*)Brep_l + ((size_t)jb * 120 + 30 * w) * 4096;

  f32x4 acc[4][4] = {};
  gemm_pipe<30>(aw, bw, lane_off, acc);

#pragma unroll
  for (int mt = 0; mt < 4; ++mt)
#pragma unroll
    for (int nt = 0; nt < 4; ++nt)
      *(f32x4*)&red[w][nt][ln][mt * 16 + quad * 4] = acc[mt][nt];
  __syncthreads();

  f32x4 g[4];
#pragma unroll
  for (int nt = 0; nt < 4; ++nt) {
    f32x4 s = *(const f32x4*)&red[0][nt][ln][w * 16 + quad * 4];
#pragma unroll
    for (int p = 1; p < 4; ++p) {
      f32x4 tv = *(const f32x4*)&red[p][nt][ln][w * 16 + quad * 4];
      s[0] += tv[0]; s[1] += tv[1]; s[2] += tv[2]; s[3] += tv[3];
    }
    g[nt] = s;
  }

  const int kh = jb * 16 + ln;
  const int chl = kh >> 5, quad2 = (kh >> 3) & 3, jj = kh & 7;
  float bs[4];
#pragma unroll
  for (int gi = 0; gi < 4; ++gi) bs[gi] = bih_l[gi * 1920 + kh] + bhh_l[gi * 1920 + kh];
#pragma unroll
  for (int r = 0; r < 4; ++r) {
    int m = mh * 64 + w * 16 + quad * 4 + r;
    float vi = g[0][r] + bs[0];
    float vf = g[1][r] + bs[1];
    float vg = g[2][r] + bs[2];
    float vo = g[3][r] + bs[3];
    size_t ci = (size_t)m * 1920 + kh;
    float cn = sigm(vf) * c_l[ci] + sigm(vi) * tanhfast(vg);
    float hn = sigm(vo) * tanhfast(cn);
    c_l[ci] = cn;
    u16 hb = f2bf(hn);
    int lane2 = quad2 * 16 + quad * 4 + r;
    size_t hi = ((size_t)(mh * 180 + chl) * 4 + w) * 512 + lane2 * 8 + jj;
    hA[hi] = hb;
    size_t hi2 = ((size_t)(mh * sB + chl) * 4 + w) * 512 + lane2 * 8 + jj;
    hB[hi2] = hb;
  }
  // NOTE: intra-block LDS reuse across phases is fenced by gridbar()'s
  // __syncthreads(); cross-block visibility by its agent fences.
}

// W3 GEMM + relu (blocks 0..59 only): nb = bid%30, mh = bid/30
__device__ __forceinline__ void w3_phase(const u16* __restrict__ A2,
                                         const u16* __restrict__ W3r,
                                         const float* __restrict__ b3,
                                         u16* __restrict__ X3b,
                                         float (*red)[4][16][64], int bid, int tid) {
  const int w = tid >> 6;
  const int lane = tid & 63;
  const int ln = lane & 15, quad = lane >> 4;
  const int nb = bid % 30;
  const int mh = bid / 30;
  const int lane_off = lane * 16;

  const char* aw = (const char*)A2 + ((size_t)mh * 60 + 15 * w) * 4096;
  const char* bw = (const char*)W3r + ((size_t)nb * 60 + 15 * w) * 4096;

  f32x4 acc[4][4] = {};
  gemm_pipe<15>(aw, bw, lane_off, acc);

#pragma unroll
  for (int mt = 0; mt < 4; ++mt)
#pragma unroll
    for (int nt = 0; nt < 4; ++nt)
      *(f32x4*)&red[w][nt][ln][mt * 16 + quad * 4] = acc[mt][nt];
  __syncthreads();

#pragma unroll
  for (int nt = 0; nt < 4; ++nt) {
    f32x4 s = *(const f32x4*)&red[0][nt][ln][w * 16 + quad * 4];
#pragma unroll
    for (int p = 1; p < 4; ++p) {
      f32x4 tv = *(const f32x4*)&red[p][nt][ln][w * 16 + quad * 4];
      s[0] += tv[0]; s[1] += tv[1]; s[2] += tv[2]; s[3] += tv[3];
    }
    int n = nb * 64 + nt * 16 + ln;
    float bias = b3[n];
#pragma unroll
    for (int r = 0; r < 4; ++r) {
      int m = mh * 64 + w * 16 + quad * 4 + r;
      X3b[(size_t)m * 1920 + n] = f2bf(fmaxf(s[r] + bias, 0.f));
    }
  }
}

// ---------------- the persistent time-loop kernel ----------------
// 240 blocks x 256 threads. One launch replaces 320 dependent graph nodes.
__global__ __launch_bounds__(256, 1) void k_persist(
    const float* __restrict__ inputs, const float* __restrict__ W1,
    const float* __restrict__ b1, const float* __restrict__ W2,
    const float* __restrict__ b2, const float* __restrict__ bih,
    const float* __restrict__ bhh, const float* __restrict__ b3,
    const float* __restrict__ W4, const float* __restrict__ b4,
    const int* __restrict__ burn, const u16* __restrict__ Brep,
    const u16* __restrict__ W3r, float* __restrict__ cbuf,
    u16* __restrict__ A0, u16* __restrict__ A1, u16* __restrict__ A2,
    u16* __restrict__ X3b, float* __restrict__ insb,
    float* __restrict__ prevb, float* __restrict__ outp) {
  __shared__ float red[4][4][16][64];  // 64 KB, reused by every phase
  const int bid = blockIdx.x;
  const int tid = threadIdx.x;
  const int bn = *burn;
  const size_t BrepL = (size_t)120 * 120 * 2048;

  for (int t = 0; t < 64; ++t) {
    const int p = t & 1;
    const int rd_off = 60 + p * 60;
    const int wr_off = 60 + (1 - p) * 60;

    // ---- phase 1: ins-select + per-atom MLP (16 pairs per block) ----
    {
      const int w = tid >> 6, j = tid & 63;
      float* h1s = (float*)red;  // [4 waves][64]
      const bool gt = (t <= bn);
      for (int pi = 0; pi < 4; ++pi) {
        const int ba = bid * 16 + w * 4 + pi;  // 240*16 = 3840 pairs
        const int b = ba / 30, a = ba % 30;
        const float* src = gt ? (inputs + (((size_t)ba) * 65 + t) * 4)
                              : (prevb + (size_t)ba * 4);
        float i0 = src[0], i1 = src[1], i2 = src[2], i3 = src[3];
        float h1 = b1[j] + i0 * W1[j * 4 + 0] + i1 * W1[j * 4 + 1] +
                   i2 * W1[j * 4 + 2] + i3 * W1[j * 4 + 3];
        h1 = fmaxf(h1, 0.f);
        h1s[w * 64 + j] = h1;
        __syncthreads();
        float h2 = b2[j];
        const float* w2r = W2 + j * 64;
#pragma unroll 8
        for (int k = 0; k < 64; ++k) h2 += h1s[w * 64 + k] * w2r[k];
        h2 = fmaxf(h2, 0.f);
        int mh = b >> 6, mloc = b & 63, mt = mloc >> 4, ln2 = mloc & 15;
        int ch = a * 2 + (j >> 5), quad2 = (j >> 3) & 3, jj = j & 7;
        size_t xi = ((size_t)(mh * 180 + ch) * 4 + mt) * 512 + (quad2 * 16 + ln2) * 8 + jj;
        A0[xi] = f2bf(h2);
        if (j < 4) insb[(size_t)ba * 4 + j] = src[j];
        __syncthreads();
      }
    }
    gridbar();

    // ---- phase 2: LSTM layer 0 gates + cell ----
    gates_phase(A0, Brep, bih, bhh, cbuf,
                A0 + (size_t)wr_off * 2048, A1, rd_off, 180, red, bid, tid);
    gridbar();

    // ---- phase 3: LSTM layer 1 gates + cell ----
    gates_phase(A1, Brep + BrepL, bih + 7680, bhh + 7680, cbuf + 245760,
                A1 + (size_t)wr_off * 2048, A2, rd_off, 60, red, bid, tid);
    gridbar();

    // ---- phase 4: W3 GEMM + relu (60 blocks active) ----
    if (bid < 60) w3_phase(A2, W3r, b3, X3b, red, bid, tid);
    gridbar();

    // ---- phase 5: W4 projection + bias + residual (8 units per block) ----
    {
      const int w = tid >> 6, lane = tid & 63;
      for (int ui = 0; ui < 2; ++ui) {
        int unit = bid * 8 + w * 2 + ui;  // 240*8 = 1920 units
        int m = unit / 15;
        int pb = unit % 15;
        const u16* xr = X3b + (size_t)m * 1920;
        float xv[30];
#pragma unroll
        for (int i = 0; i < 30; ++i) xv[i] = bf2f(xr[lane + 64 * i]);
#pragma unroll 1
        for (int pi = 0; pi < 8; ++pi) {
          int pp = pb * 8 + pi;
          const float* wr = W4 + (size_t)pp * 1920;
          float s = 0.f;
#pragma unroll
          for (int i = 0; i < 30; ++i) s += xv[i] * wr[lane + 64 * i];
#pragma unroll
          for (int off = 32; off > 0; off >>= 1) s += __shfl_xor(s, off);
          if (lane == 0) {
            float v = s + b4[pp] + insb[(size_t)m * 120 + pp];
            outp[(((size_t)m * 30 + (pp >> 2)) * 64 + t) * 4 + (pp & 3)] = v;
            prevb[(size_t)m * 120 + pp] = v;
          }
        }
      }
    }
    gridbar();  // prevb/outp visible before phase 1 of t+1
  }
}

extern "C" void kernel_launch(void* const* d_in, const int* in_sizes, int n_in,
                              void* d_out, int out_size, void* d_ws, size_t ws_size,
                              hipStream_t stream) {
  (void)in_sizes; (void)n_in; (void)out_size;
  const float* inputs = (const float*)d_in[0];
  const float* W1 = (const float*)d_in[1];
  const float* b1 = (const float*)d_in[2];
  const float* W2 = (const float*)d_in[3];
  const float* b2 = (const float*)d_in[4];
  const float* Wih = (const float*)d_in[5];
  const float* Whh = (const float*)d_in[6];
  const float* bih = (const float*)d_in[7];
  const float* bhh = (const float*)d_in[8];
  const float* W3 = (const float*)d_in[9];
  const float* b3 = (const float*)d_in[10];
  const float* W4 = (const float*)d_in[11];
  const float* b4 = (const float*)d_in[12];
  const int* burn = (const int*)d_in[14];
  float* outp = (float*)d_out;
  char* ws = (char*)d_ws;

  // ---- workspace layout (bytes) ----
  float* cbuf = (float*)ws;                          // [2][128][1920] f32
  u16* A0 = (u16*)(ws + 1966080);                    // [2mh][180ch][4][512] u16
  u16* A1 = (u16*)(ws + 3440640);
  u16* A2 = (u16*)(ws + 4915200);                    // [2mh][60ch][4][512] u16
  u16* X3b = (u16*)(ws + 5406720);                   // [128][1920] bf16
  float* insb = (float*)(ws + 5898240);              // [128][120]
  float* prevb = (float*)(ws + 5959680);             // [128][120]
  u16* Brep = (u16*)(ws + 6021120);                  // 58982400 u16
  u16* W3r = (u16*)(ws + 123985920);                 // 3686400 u16
  if (ws_size < 131358720) return;                   // insufficient scratch

  // zero c + A0 + A1 (1228800 floats)
  hipLaunchKernelGGL(k_zero, dim3(4800), dim3(256), 0, stream, (float*)ws);
  // repack weights to bf16 fragment-tiled
  hipLaunchKernelGGL(k_repB, dim3(28800), dim3(256), 0, stream, Wih, Whh, Brep);
  hipLaunchKernelGGL(k_repW3, dim3(1800), dim3(256), 0, stream, W3, W3r);

  // one persistent kernel for the whole 64-step loop
  hipLaunchKernelGGL(k_persist, dim3(240), dim3(256), 0, stream,
                     inputs, W1, b1, W2, b2, bih, bhh, b3, W4, b4, burn,
                     Brep, W3r, cbuf, A0, A1, A2, X3b, insb, prevb, outp);
}

// Round 6
// 17107.356 us; speedup vs baseline: 1.4751x; 1.4751x over previous
//
#include <hip/hip_runtime.h>
#include <stdint.h>

typedef unsigned short u16;
typedef __attribute__((ext_vector_type(8))) short bf16x8;
typedef __attribute__((ext_vector_type(4))) float f32x4;
typedef __attribute__((ext_vector_type(4))) u16 u16x4;

__device__ __forceinline__ u16 f2bf(float f) {
  union { float f; uint32_t u; } v; v.f = f;
  uint32_t u = v.u;
  uint32_t r = u + 0x7fffu + ((u >> 16) & 1u);
  return (u16)(r >> 16);
}
__device__ __forceinline__ float bf2f(u16 h) {
  union { uint32_t u; float f; } v; v.u = ((uint32_t)h) << 16; return v.f;
}
__device__ __forceinline__ float sigm(float x) { return 1.f / (1.f + __expf(-x)); }
__device__ __forceinline__ float tanhfast(float x) {
  float t = __expf(-2.f * fabsf(x));
  float r = (1.f - t) / (1.f + t);
  return x < 0.f ? -r : r;
}

// Write-through stores (sc0 sc1: bypass L1/L2, land in IC/memory -> visible to
// all XCDs' subsequent cache-miss loads). Used for ALL cross-block data.
__device__ __forceinline__ void wt16(u16* p, u16 v) {
  asm volatile("global_store_short %0, %1, off sc0 sc1"
               :: "v"(p), "v"((uint32_t)v) : "memory");
}
__device__ __forceinline__ void wt32(float* p, float v) {
  asm volatile("global_store_dword %0, %1, off sc0 sc1"
               :: "v"(p), "v"(v) : "memory");
}

__global__ __launch_bounds__(256) void k_zero(float* __restrict__ p) {
  p[(size_t)blockIdx.x * 256 + threadIdx.x] = 0.f;
}

// Repack Wih||Whh (fp32) -> bf16 fragment-tiled: [l][jb(120)][k0(120)][g(4)][lane(64)][8]
__global__ __launch_bounds__(256) void k_repB(const float* __restrict__ Wih,
                                              const float* __restrict__ Whh,
                                              u16* __restrict__ dst) {
  int e8 = blockIdx.x * 256 + threadIdx.x;
  if (e8 >= 7372800) return;
  int lane = e8 & 63;
  int t1 = e8 >> 6;
  int g = t1 & 3;
  int t2 = t1 >> 2;
  int k0 = t2 % 120;
  int t3 = t2 / 120;
  int jb = t3 % 120;
  int l = t3 / 120;
  int ln = lane & 15, quad = lane >> 4;
  int n = g * 1920 + jb * 16 + ln;
  const float* src = (k0 < 60)
      ? (Wih + ((size_t)(l * 7680 + n)) * 1920 + k0 * 32 + quad * 8)
      : (Whh + ((size_t)(l * 7680 + n)) * 1920 + (k0 - 60) * 32 + quad * 8);
  float4 a = ((const float4*)src)[0];
  float4 b = ((const float4*)src)[1];
  u16x4 o0, o1;
  o0[0] = f2bf(a.x); o0[1] = f2bf(a.y); o0[2] = f2bf(a.z); o0[3] = f2bf(a.w);
  o1[0] = f2bf(b.x); o1[1] = f2bf(b.y); o1[2] = f2bf(b.z); o1[3] = f2bf(b.w);
  ((u16x4*)(dst + (size_t)e8 * 8))[0] = o0;
  ((u16x4*)(dst + (size_t)e8 * 8))[1] = o1;
}

// Repack W3 (fp32 [1920,1920]) -> [nb(30)][k0(60)][nt(4)][lane(64)][8]
__global__ __launch_bounds__(256) void k_repW3(const float* __restrict__ W3,
                                               u16* __restrict__ dst) {
  int e8 = blockIdx.x * 256 + threadIdx.x;
  if (e8 >= 460800) return;
  int lane = e8 & 63;
  int t1 = e8 >> 6;
  int nt = t1 & 3;
  int t2 = t1 >> 2;
  int k0 = t2 % 60;
  int nb = t2 / 60;
  int ln = lane & 15, quad = lane >> 4;
  int n = nb * 64 + nt * 16 + ln;
  const float* src = W3 + (size_t)n * 1920 + k0 * 32 + quad * 8;
  float4 a = ((const float4*)src)[0];
  float4 b = ((const float4*)src)[1];
  u16x4 o0, o1;
  o0[0] = f2bf(a.x); o0[1] = f2bf(a.y); o0[2] = f2bf(a.z); o0[3] = f2bf(a.w);
  o1[0] = f2bf(b.x); o1[1] = f2bf(b.y); o1[2] = f2bf(b.z); o1[3] = f2bf(b.w);
  ((u16x4*)(dst + (size_t)e8 * 8))[0] = o0;
  ((u16x4*)(dst + (size_t)e8 * 8))[1] = o1;
}

// Rolling-pipeline fragment GEMM: ITERS k-iters (32 k each), depth 5.
template <int ITERS>
__device__ __forceinline__ void gemm_pipe(const char* __restrict__ aw,
                                          const char* __restrict__ bw,
                                          int lane_off, f32x4 acc[4][4]) {
  constexpr int D = 5;
  bf16x8 Af[D][4], Bf[D][4];
#pragma unroll
  for (int p = 0; p < D; ++p) {
#pragma unroll
    for (int mt = 0; mt < 4; ++mt)
      Af[p][mt] = *(const bf16x8*)(aw + p * 4096 + mt * 1024 + lane_off);
#pragma unroll
    for (int nt = 0; nt < 4; ++nt)
      Bf[p][nt] = *(const bf16x8*)(bw + p * 4096 + nt * 1024 + lane_off);
  }
  for (int o = 0; o < (ITERS - D) / D; ++o) {
    const char* ap = aw + (size_t)(o + 1) * (D * 4096);
    const char* bp = bw + (size_t)(o + 1) * (D * 4096);
#pragma unroll
    for (int d = 0; d < D; ++d) {
#pragma unroll
      for (int mt = 0; mt < 4; ++mt)
#pragma unroll
        for (int nt = 0; nt < 4; ++nt)
          acc[mt][nt] = __builtin_amdgcn_mfma_f32_16x16x32_bf16(
              Af[d][mt], Bf[d][nt], acc[mt][nt], 0, 0, 0);
#pragma unroll
      for (int mt = 0; mt < 4; ++mt)
        Af[d][mt] = *(const bf16x8*)(ap + d * 4096 + mt * 1024 + lane_off);
#pragma unroll
      for (int nt = 0; nt < 4; ++nt)
        Bf[d][nt] = *(const bf16x8*)(bp + d * 4096 + nt * 1024 + lane_off);
    }
  }
#pragma unroll
  for (int d = 0; d < D; ++d) {
#pragma unroll
    for (int mt = 0; mt < 4; ++mt)
#pragma unroll
      for (int nt = 0; nt < 4; ++nt)
        acc[mt][nt] = __builtin_amdgcn_mfma_f32_16x16x32_bf16(
            Af[d][mt], Bf[d][nt], acc[mt][nt], 0, 0, 0);
  }
}

// ---------------- persistent-kernel infrastructure ----------------
// Two-level sense barrier. 8 groups x 30 blocks; every hot word on its own
// 256B line (separate L3 slices) to kill same-line contention that throttled
// round 2 (240 RMWs + 239 pollers on ONE line -> ~60us/barrier).
// All atomics RELAXED: acquire/release ATOMICS on gfx950 emit whole-L2
// buffer_inv/buffer_wbl2 -- explicitly avoided. Ordering via s_waitcnt.
// Coherence model: cross-block data is written with sc0+sc1 write-through
// stores (visible in IC); readers use normal cached loads, made safe by ONE
// __threadfence (L1+L2 invalidate) per step at the post-MLP barrier. Every
// rewritten buffer's stale-window contains that fence (verified per-buffer).
__device__ __align__(256) unsigned g_ctr[8 * 64];
__device__ __align__(256) unsigned g_root[64];
__device__ __align__(256) unsigned g_gen[8 * 64];

__device__ __forceinline__ void gridbar(int grp, bool do_inv) {
  __syncthreads();  // HIP semantics: drains vmcnt(0) -> all sc-stores visible
  if (threadIdx.x == 0) {
    unsigned G = __hip_atomic_load(&g_gen[grp << 6], __ATOMIC_RELAXED,
                                   __HIP_MEMORY_SCOPE_AGENT);
    asm volatile("s_waitcnt vmcnt(0)" ::: "memory");  // G read before arrival
    unsigned a = __hip_atomic_fetch_add(&g_ctr[grp << 6], 1u, __ATOMIC_RELAXED,
                                        __HIP_MEMORY_SCOPE_AGENT) + 1u;
    if (a == 30u) {
      __hip_atomic_store(&g_ctr[grp << 6], 0u, __ATOMIC_RELAXED,
                         __HIP_MEMORY_SCOPE_AGENT);
      asm volatile("s_waitcnt vmcnt(0)" ::: "memory");  // reset lands pre-root
      unsigned r = __hip_atomic_fetch_add(&g_root[0], 1u, __ATOMIC_RELAXED,
                                          __HIP_MEMORY_SCOPE_AGENT) + 1u;
      if (r == 8u) {
        __hip_atomic_store(&g_root[0], 0u, __ATOMIC_RELAXED,
                           __HIP_MEMORY_SCOPE_AGENT);
        asm volatile("s_waitcnt vmcnt(0)" ::: "memory");  // root reset first
#pragma unroll
        for (int i = 0; i < 8; ++i)
          __hip_atomic_store(&g_gen[i << 6], G + 1u, __ATOMIC_RELAXED,
                             __HIP_MEMORY_SCOPE_AGENT);
      } else {
        while (__hip_atomic_load(&g_gen[grp << 6], __ATOMIC_RELAXED,
                                 __HIP_MEMORY_SCOPE_AGENT) == G)
          __builtin_amdgcn_s_sleep(8);
      }
    } else {
      while (__hip_atomic_load(&g_gen[grp << 6], __ATOMIC_RELAXED,
                               __HIP_MEMORY_SCOPE_AGENT) == G)
        __builtin_amdgcn_s_sleep(8);
    }
    if (do_inv) __threadfence();  // once per step: L1+L2 invalidate window
  }
  __syncthreads();
}

// Gates GEMM + fused LSTM cell phase. 240 blocks: jb = bid%120, mh = bid/120.
__device__ __forceinline__ void gates_phase(
    const u16* __restrict__ Atl, const u16* __restrict__ Brep_l,
    const float* __restrict__ bih_l, const float* __restrict__ bhh_l,
    float* __restrict__ c_l, u16* __restrict__ hA, u16* __restrict__ hB,
    int rd_off, int sB, float (*red)[4][16][64], int bid, int tid) {
  const int w = tid >> 6;
  const int lane = tid & 63;
  const int ln = lane & 15, quad = lane >> 4;
  const int jb = bid % 120;
  const int mh = bid / 120;
  const int lane_off = lane * 16;

  const char* ax = (const char*)Atl + (size_t)mh * 180 * 4096;
  const char* ah = ax + (size_t)rd_off * 4096;
  const char* aw = (w < 2) ? (ax + (size_t)(30 * w) * 4096)
                           : (ah + (size_t)(30 * (w - 2)) * 4096);
  const char* bw = (const char*)Brep_l + ((size_t)jb * 120 + 30 * w) * 4096;

  f32x4 acc[4][4] = {};
  gemm_pipe<30>(aw, bw, lane_off, acc);

#pragma unroll
  for (int mt = 0; mt < 4; ++mt)
#pragma unroll
    for (int nt = 0; nt < 4; ++nt)
      *(f32x4*)&red[w][nt][ln][mt * 16 + quad * 4] = acc[mt][nt];
  __syncthreads();

  f32x4 g[4];
#pragma unroll
  for (int nt = 0; nt < 4; ++nt) {
    f32x4 s = *(const f32x4*)&red[0][nt][ln][w * 16 + quad * 4];
#pragma unroll
    for (int p = 1; p < 4; ++p) {
      f32x4 tv = *(const f32x4*)&red[p][nt][ln][w * 16 + quad * 4];
      s[0] += tv[0]; s[1] += tv[1]; s[2] += tv[2]; s[3] += tv[3];
    }
    g[nt] = s;
  }

  const int kh = jb * 16 + ln;
  const int chl = kh >> 5, quad2 = (kh >> 3) & 3, jj = kh & 7;
  float bs[4];
#pragma unroll
  for (int gi = 0; gi < 4; ++gi) bs[gi] = bih_l[gi * 1920 + kh] + bhh_l[gi * 1920 + kh];
#pragma unroll
  for (int r = 0; r < 4; ++r) {
    int m = mh * 64 + w * 16 + quad * 4 + r;
    float vi = g[0][r] + bs[0];
    float vf = g[1][r] + bs[1];
    float vg = g[2][r] + bs[2];
    float vo = g[3][r] + bs[3];
    size_t ci = (size_t)m * 1920 + kh;
    float cn = sigm(vf) * c_l[ci] + sigm(vi) * tanhfast(vg);
    float hn = sigm(vo) * tanhfast(cn);
    c_l[ci] = cn;                       // block-private across steps: cached
    u16 hb = f2bf(hn);
    int lane2 = quad2 * 16 + quad * 4 + r;
    size_t hi = ((size_t)(mh * 180 + chl) * 4 + w) * 512 + lane2 * 8 + jj;
    wt16(hA + hi, hb);                  // cross-block: write-through
    size_t hi2 = ((size_t)(mh * sB + chl) * 4 + w) * 512 + lane2 * 8 + jj;
    wt16(hB + hi2, hb);                 // cross-block: write-through
  }
}

// W3 GEMM + relu (blocks 0..59 only): nb = bid%30, mh = bid/30
__device__ __forceinline__ void w3_phase(const u16* __restrict__ A2,
                                         const u16* __restrict__ W3r,
                                         const float* __restrict__ b3,
                                         u16* __restrict__ X3b,
                                         float (*red)[4][16][64], int bid, int tid) {
  const int w = tid >> 6;
  const int lane = tid & 63;
  const int ln = lane & 15, quad = lane >> 4;
  const int nb = bid % 30;
  const int mh = bid / 30;
  const int lane_off = lane * 16;

  const char* aw = (const char*)A2 + ((size_t)mh * 60 + 15 * w) * 4096;
  const char* bw = (const char*)W3r + ((size_t)nb * 60 + 15 * w) * 4096;

  f32x4 acc[4][4] = {};
  gemm_pipe<15>(aw, bw, lane_off, acc);

#pragma unroll
  for (int mt = 0; mt < 4; ++mt)
#pragma unroll
    for (int nt = 0; nt < 4; ++nt)
      *(f32x4*)&red[w][nt][ln][mt * 16 + quad * 4] = acc[mt][nt];
  __syncthreads();

#pragma unroll
  for (int nt = 0; nt < 4; ++nt) {
    f32x4 s = *(const f32x4*)&red[0][nt][ln][w * 16 + quad * 4];
#pragma unroll
    for (int p = 1; p < 4; ++p) {
      f32x4 tv = *(const f32x4*)&red[p][nt][ln][w * 16 + quad * 4];
      s[0] += tv[0]; s[1] += tv[1]; s[2] += tv[2]; s[3] += tv[3];
    }
    int n = nb * 64 + nt * 16 + ln;
    float bias = b3[n];
#pragma unroll
    for (int r = 0; r < 4; ++r) {
      int m = mh * 64 + w * 16 + quad * 4 + r;
      wt16(X3b + (size_t)m * 1920 + n, f2bf(fmaxf(s[r] + bias, 0.f)));
    }
  }
}

// ---------------- the persistent time-loop kernel ----------------
// 240 blocks x 256 threads. One launch replaces 320 dependent graph nodes.
__global__ __launch_bounds__(256, 1) void k_persist(
    const float* __restrict__ inputs, const float* __restrict__ W1,
    const float* __restrict__ b1, const float* __restrict__ W2,
    const float* __restrict__ b2, const float* __restrict__ bih,
    const float* __restrict__ bhh, const float* __restrict__ b3,
    const float* __restrict__ W4, const float* __restrict__ b4,
    const int* __restrict__ burn, const u16* __restrict__ Brep,
    const u16* __restrict__ W3r, float* __restrict__ cbuf,
    u16* __restrict__ A0, u16* __restrict__ A1, u16* __restrict__ A2,
    u16* __restrict__ X3b, float* __restrict__ insb,
    float* __restrict__ prevb, float* __restrict__ outp) {
  __shared__ float red[4][4][16][64];  // 64 KB, reused by every phase
  const int bid = blockIdx.x;
  const int tid = threadIdx.x;
  const int grp = bid / 30;            // 8 barrier groups of 30 blocks
  const int bn = *burn;
  const size_t BrepL = (size_t)120 * 120 * 2048;

  for (int t = 0; t < 64; ++t) {
    const int p = t & 1;
    const int rd_off = 60 + p * 60;
    const int wr_off = 60 + (1 - p) * 60;

    // ---- phase 1: ins-select + per-atom MLP (16 pairs per block) ----
    {
      const int w = tid >> 6, j = tid & 63;
      float* h1s = (float*)red;  // [4 waves][64]
      const bool gt = (t <= bn);
      for (int pi = 0; pi < 4; ++pi) {
        const int ba = bid * 16 + w * 4 + pi;  // 240*16 = 3840 pairs
        const int b = ba / 30, a = ba % 30;
        const float* src = gt ? (inputs + (((size_t)ba) * 65 + t) * 4)
                              : (prevb + (size_t)ba * 4);
        float i0 = src[0], i1 = src[1], i2 = src[2], i3 = src[3];
        float h1 = b1[j] + i0 * W1[j * 4 + 0] + i1 * W1[j * 4 + 1] +
                   i2 * W1[j * 4 + 2] + i3 * W1[j * 4 + 3];
        h1 = fmaxf(h1, 0.f);
        h1s[w * 64 + j] = h1;
        __syncthreads();
        float h2 = b2[j];
        const float* w2r = W2 + j * 64;
#pragma unroll 8
        for (int k = 0; k < 64; ++k) h2 += h1s[w * 64 + k] * w2r[k];
        h2 = fmaxf(h2, 0.f);
        int mh = b >> 6, mloc = b & 63, mt = mloc >> 4, ln2 = mloc & 15;
        int ch = a * 2 + (j >> 5), quad2 = (j >> 3) & 3, jj = j & 7;
        size_t xi = ((size_t)(mh * 180 + ch) * 4 + mt) * 512 + (quad2 * 16 + ln2) * 8 + jj;
        wt16(A0 + xi, f2bf(h2));                       // cross-block
        if (j < 4) wt32(insb + (size_t)ba * 4 + j, src[j]);  // cross-block
        __syncthreads();
      }
    }
    gridbar(grp, true);  // the ONE per-step L1/L2 invalidate lives here

    // ---- phase 2: LSTM layer 0 gates + cell ----
    gates_phase(A0, Brep, bih, bhh, cbuf,
                A0 + (size_t)wr_off * 2048, A1, rd_off, 180, red, bid, tid);
    gridbar(grp, false);

    // ---- phase 3: LSTM layer 1 gates + cell ----
    gates_phase(A1, Brep + BrepL, bih + 7680, bhh + 7680, cbuf + 245760,
                A1 + (size_t)wr_off * 2048, A2, rd_off, 60, red, bid, tid);
    gridbar(grp, false);

    // ---- phase 4: W3 GEMM + relu (60 blocks active) ----
    if (bid < 60) w3_phase(A2, W3r, b3, X3b, red, bid, tid);
    gridbar(grp, false);

    // ---- phase 5: W4 projection + bias + residual (8 units per block) ----
    {
      const int w = tid >> 6, lane = tid & 63;
      for (int ui = 0; ui < 2; ++ui) {
        int unit = bid * 8 + w * 2 + ui;  // 240*8 = 1920 units
        int m = unit / 15;
        int pb = unit % 15;
        const u16* xr = X3b + (size_t)m * 1920;
        float xv[30];
#pragma unroll
        for (int i = 0; i < 30; ++i) xv[i] = bf2f(xr[lane + 64 * i]);
#pragma unroll 1
        for (int pi = 0; pi < 8; ++pi) {
          int pp = pb * 8 + pi;
          const float* wr = W4 + (size_t)pp * 1920;
          float s = 0.f;
#pragma unroll
          for (int i = 0; i < 30; ++i) s += xv[i] * wr[lane + 64 * i];
#pragma unroll
          for (int off = 32; off > 0; off >>= 1) s += __shfl_xor(s, off);
          if (lane == 0) {
            float v = s + b4[pp] + insb[(size_t)m * 120 + pp];
            outp[(((size_t)m * 30 + (pp >> 2)) * 64 + t) * 4 + (pp & 3)] = v;
            wt32(prevb + (size_t)m * 120 + pp, v);   // cross-block
          }
        }
      }
    }
    gridbar(grp, false);  // prevb visible before phase 1 of t+1
  }
}

extern "C" void kernel_launch(void* const* d_in, const int* in_sizes, int n_in,
                              void* d_out, int out_size, void* d_ws, size_t ws_size,
                              hipStream_t stream) {
  (void)in_sizes; (void)n_in; (void)out_size;
  const float* inputs = (const float*)d_in[0];
  const float* W1 = (const float*)d_in[1];
  const float* b1 = (const float*)d_in[2];
  const float* W2 = (const float*)d_in[3];
  const float* b2 = (const float*)d_in[4];
  const float* Wih = (const float*)d_in[5];
  const float* Whh = (const float*)d_in[6];
  const float* bih = (const float*)d_in[7];
  const float* bhh = (const float*)d_in[8];
  const float* W3 = (const float*)d_in[9];
  const float* b3 = (const float*)d_in[10];
  const float* W4 = (const float*)d_in[11];
  const float* b4 = (const float*)d_in[12];
  const int* burn = (const int*)d_in[14];
  float* outp = (float*)d_out;
  char* ws = (char*)d_ws;

  // ---- workspace layout (bytes) ----
  float* cbuf = (float*)ws;                          // [2][128][1920] f32
  u16* A0 = (u16*)(ws + 1966080);                    // [2mh][180ch][4][512] u16
  u16* A1 = (u16*)(ws + 3440640);
  u16* A2 = (u16*)(ws + 4915200);                    // [2mh][60ch][4][512] u16
  u16* X3b = (u16*)(ws + 5406720);                   // [128][1920] bf16
  float* insb = (float*)(ws + 5898240);              // [128][120]
  float* prevb = (float*)(ws + 5959680);             // [128][120]
  u16* Brep = (u16*)(ws + 6021120);                  // 58982400 u16
  u16* W3r = (u16*)(ws + 123985920);                 // 3686400 u16
  if (ws_size < 131358720) return;                   // insufficient scratch

  // zero c + A0 + A1 (1228800 floats)
  hipLaunchKernelGGL(k_zero, dim3(4800), dim3(256), 0, stream, (float*)ws);
  // repack weights to bf16 fragment-tiled
  hipLaunchKernelGGL(k_repB, dim3(28800), dim3(256), 0, stream, Wih, Whh, Brep);
  hipLaunchKernelGGL(k_repW3, dim3(1800), dim3(256), 0, stream, W3, W3r);

  // one persistent kernel for the whole 64-step loop
  hipLaunchKernelGGL(k_persist, dim3(240), dim3(256), 0, stream,
                     inputs, W1, b1, W2, b2, bih, bhh, b3, W4, b4, burn,
                     Brep, W3r, cbuf, A0, A1, A2, X3b, insb, prevb, outp);
}

// Round 13
// 5974.017 us; speedup vs baseline: 4.2240x; 2.8636x over previous
//
#include <hip/hip_runtime.h>
#include <stdint.h>

typedef unsigned short u16;
typedef __attribute__((ext_vector_type(8))) short bf16x8;
typedef __attribute__((ext_vector_type(4))) float f32x4;
typedef __attribute__((ext_vector_type(4))) u16 u16x4;

__device__ __forceinline__ u16 f2bf(float f) {
  union { float f; uint32_t u; } v; v.f = f;
  uint32_t u = v.u;
  uint32_t r = u + 0x7fffu + ((u >> 16) & 1u);
  return (u16)(r >> 16);
}
__device__ __forceinline__ float bf2f(u16 h) {
  union { uint32_t u; float f; } v; v.u = ((uint32_t)h) << 16; return v.f;
}
__device__ __forceinline__ float sigm(float x) { return 1.f / (1.f + __expf(-x)); }
__device__ __forceinline__ float tanhfast(float x) {
  float t = __expf(-2.f * fabsf(x));
  float r = (1.f - t) / (1.f + t);
  return x < 0.f ? -r : r;
}

__global__ __launch_bounds__(256) void k_zero(float* __restrict__ p) {
  p[(size_t)blockIdx.x * 256 + threadIdx.x] = 0.f;
}

// Repack Wih||Whh (fp32) -> bf16 fragment-tiled: [l][jb(120)][k0(120)][g(4)][lane(64)][8]
__global__ __launch_bounds__(256) void k_repB(const float* __restrict__ Wih,
                                              const float* __restrict__ Whh,
                                              u16* __restrict__ dst) {
  int e8 = blockIdx.x * 256 + threadIdx.x;
  if (e8 >= 7372800) return;
  int lane = e8 & 63;
  int t1 = e8 >> 6;
  int g = t1 & 3;
  int t2 = t1 >> 2;
  int k0 = t2 % 120;
  int t3 = t2 / 120;
  int jb = t3 % 120;
  int l = t3 / 120;
  int ln = lane & 15, quad = lane >> 4;
  int n = g * 1920 + jb * 16 + ln;
  const float* src = (k0 < 60)
      ? (Wih + ((size_t)(l * 7680 + n)) * 1920 + k0 * 32 + quad * 8)
      : (Whh + ((size_t)(l * 7680 + n)) * 1920 + (k0 - 60) * 32 + quad * 8);
  float4 a = ((const float4*)src)[0];
  float4 b = ((const float4*)src)[1];
  u16x4 o0, o1;
  o0[0] = f2bf(a.x); o0[1] = f2bf(a.y); o0[2] = f2bf(a.z); o0[3] = f2bf(a.w);
  o1[0] = f2bf(b.x); o1[1] = f2bf(b.y); o1[2] = f2bf(b.z); o1[3] = f2bf(b.w);
  ((u16x4*)(dst + (size_t)e8 * 8))[0] = o0;
  ((u16x4*)(dst + (size_t)e8 * 8))[1] = o1;
}

// Repack W3 (fp32 [1920,1920]) -> [nb(30)][k0(60)][nt(4)][lane(64)][8]
__global__ __launch_bounds__(256) void k_repW3(const float* __restrict__ W3,
                                               u16* __restrict__ dst) {
  int e8 = blockIdx.x * 256 + threadIdx.x;
  if (e8 >= 460800) return;
  int lane = e8 & 63;
  int t1 = e8 >> 6;
  int nt = t1 & 3;
  int t2 = t1 >> 2;
  int k0 = t2 % 60;
  int nb = t2 / 60;
  int ln = lane & 15, quad = lane >> 4;
  int n = nb * 64 + nt * 16 + ln;
  const float* src = W3 + (size_t)n * 1920 + k0 * 32 + quad * 8;
  float4 a = ((const float4*)src)[0];
  float4 b = ((const float4*)src)[1];
  u16x4 o0, o1;
  o0[0] = f2bf(a.x); o0[1] = f2bf(a.y); o0[2] = f2bf(a.z); o0[3] = f2bf(a.w);
  o1[0] = f2bf(b.x); o1[1] = f2bf(b.y); o1[2] = f2bf(b.z); o1[3] = f2bf(b.w);
  ((u16x4*)(dst + (size_t)e8 * 8))[0] = o0;
  ((u16x4*)(dst + (size_t)e8 * 8))[1] = o1;
}

// ins-select + per-atom MLP; writes X into A0 x-part (fragment-tiled) and insb
// (used ONCE, at t=0 -- later steps fuse this into k_w4mlp)
__global__ __launch_bounds__(64) void k_mlp(
    const float* __restrict__ inputs, const float* __restrict__ prevb,
    const int* __restrict__ burn,
    const float* __restrict__ W1, const float* __restrict__ b1,
    const float* __restrict__ W2, const float* __restrict__ b2,
    u16* __restrict__ A0, float* __restrict__ insb, int t) {
  __shared__ float h1s[64];
  int ba = blockIdx.x;              // b*30 + a
  int b = ba / 30, a = ba % 30;
  int j = threadIdx.x;
  bool gt = (t <= *burn);
  const float* src = gt ? (inputs + (((size_t)ba) * 65 + t) * 4)
                        : (prevb + (size_t)ba * 4);
  float i0 = src[0], i1 = src[1], i2 = src[2], i3 = src[3];
  float h1 = b1[j] + i0 * W1[j * 4 + 0] + i1 * W1[j * 4 + 1] +
             i2 * W1[j * 4 + 2] + i3 * W1[j * 4 + 3];
  h1 = fmaxf(h1, 0.f);
  h1s[j] = h1;
  __syncthreads();
  float h2 = b2[j];
  const float* w2r = W2 + j * 64;
#pragma unroll 8
  for (int k = 0; k < 64; ++k) h2 += h1s[k] * w2r[k];
  h2 = fmaxf(h2, 0.f);
  // tiled write: m=b, k=a*64+j
  int mh = b >> 6, mloc = b & 63, mt = mloc >> 4, ln2 = mloc & 15;
  int ch = a * 2 + (j >> 5), quad2 = (j >> 3) & 3, jj = j & 7;
  size_t xi = ((size_t)(mh * 180 + ch) * 4 + mt) * 512 + (quad2 * 16 + ln2) * 8 + jj;
  A0[xi] = f2bf(h2);
  if (j < 4) insb[(size_t)ba * 4 + j] = src[j];
}

// Rolling-pipeline fragment GEMM: ITERS k-iters (32 k each), depth 5.
template <int ITERS>
__device__ __forceinline__ void gemm_pipe(const char* __restrict__ aw,
                                          const char* __restrict__ bw,
                                          int lane_off, f32x4 acc[4][4]) {
  constexpr int D = 5;
  bf16x8 Af[D][4], Bf[D][4];
#pragma unroll
  for (int p = 0; p < D; ++p) {
#pragma unroll
    for (int mt = 0; mt < 4; ++mt)
      Af[p][mt] = *(const bf16x8*)(aw + p * 4096 + mt * 1024 + lane_off);
#pragma unroll
    for (int nt = 0; nt < 4; ++nt)
      Bf[p][nt] = *(const bf16x8*)(bw + p * 4096 + nt * 1024 + lane_off);
  }
  for (int o = 0; o < (ITERS - D) / D; ++o) {
    const char* ap = aw + (size_t)(o + 1) * (D * 4096);
    const char* bp = bw + (size_t)(o + 1) * (D * 4096);
#pragma unroll
    for (int d = 0; d < D; ++d) {
#pragma unroll
      for (int mt = 0; mt < 4; ++mt)
#pragma unroll
        for (int nt = 0; nt < 4; ++nt)
          acc[mt][nt] = __builtin_amdgcn_mfma_f32_16x16x32_bf16(
              Af[d][mt], Bf[d][nt], acc[mt][nt], 0, 0, 0);
#pragma unroll
      for (int mt = 0; mt < 4; ++mt)
        Af[d][mt] = *(const bf16x8*)(ap + d * 4096 + mt * 1024 + lane_off);
#pragma unroll
      for (int nt = 0; nt < 4; ++nt)
        Bf[d][nt] = *(const bf16x8*)(bp + d * 4096 + nt * 1024 + lane_off);
    }
  }
#pragma unroll
  for (int d = 0; d < D; ++d) {
#pragma unroll
    for (int mt = 0; mt < 4; ++mt)
#pragma unroll
      for (int nt = 0; nt < 4; ++nt)
        acc[mt][nt] = __builtin_amdgcn_mfma_f32_16x16x32_bf16(
            Af[d][mt], Bf[d][nt], acc[mt][nt], 0, 0, 0);
  }
}

// Gates GEMM + fused LSTM cell. grid(120 jb, 2 mh) x 256 threads (4 waves).
__global__ __launch_bounds__(256, 1) void k_gates(
    const u16* __restrict__ Atl, const u16* __restrict__ Brep_l,
    const float* __restrict__ bih_l, const float* __restrict__ bhh_l,
    float* __restrict__ c_l, u16* __restrict__ hA, u16* __restrict__ hB,
    int rd_off, int sB) {
  __shared__ float red[4][4][16][64];   // [p][nt][ln][m_local] = 64 KB
  const int tid = threadIdx.x;
  const int w = tid >> 6;
  const int lane = tid & 63;
  const int ln = lane & 15, quad = lane >> 4;
  const int jb = blockIdx.x;
  const int mh = blockIdx.y;
  const int lane_off = lane * 16;

  const char* ax = (const char*)Atl + (size_t)mh * 180 * 4096;
  const char* ah = ax + (size_t)rd_off * 4096;
  const char* aw = (w < 2) ? (ax + (size_t)(30 * w) * 4096)
                           : (ah + (size_t)(30 * (w - 2)) * 4096);
  const char* bw = (const char*)Brep_l + ((size_t)jb * 120 + 30 * w) * 4096;

  f32x4 acc[4][4] = {};
  gemm_pipe<30>(aw, bw, lane_off, acc);

#pragma unroll
  for (int mt = 0; mt < 4; ++mt)
#pragma unroll
    for (int nt = 0; nt < 4; ++nt)
      *(f32x4*)&red[w][nt][ln][mt * 16 + quad * 4] = acc[mt][nt];
  __syncthreads();

  f32x4 g[4];
#pragma unroll
  for (int nt = 0; nt < 4; ++nt) {
    f32x4 s = *(const f32x4*)&red[0][nt][ln][w * 16 + quad * 4];
#pragma unroll
    for (int p = 1; p < 4; ++p) {
      f32x4 tv = *(const f32x4*)&red[p][nt][ln][w * 16 + quad * 4];
      s[0] += tv[0]; s[1] += tv[1]; s[2] += tv[2]; s[3] += tv[3];
    }
    g[nt] = s;
  }

  const int kh = jb * 16 + ln;                 // hidden index j
  const int chl = kh >> 5, quad2 = (kh >> 3) & 3, jj = kh & 7;
  float bs[4];
#pragma unroll
  for (int gi = 0; gi < 4; ++gi) bs[gi] = bih_l[gi * 1920 + kh] + bhh_l[gi * 1920 + kh];
#pragma unroll
  for (int r = 0; r < 4; ++r) {
    int m = mh * 64 + w * 16 + quad * 4 + r;
    float vi = g[0][r] + bs[0];
    float vf = g[1][r] + bs[1];
    float vg = g[2][r] + bs[2];
    float vo = g[3][r] + bs[3];
    size_t ci = (size_t)m * 1920 + kh;
    float cn = sigm(vf) * c_l[ci] + sigm(vi) * tanhfast(vg);
    float hn = sigm(vo) * tanhfast(cn);
    c_l[ci] = cn;
    u16 hb = f2bf(hn);
    int lane2 = quad2 * 16 + quad * 4 + r;
    size_t hi = ((size_t)(mh * 180 + chl) * 4 + w) * 512 + lane2 * 8 + jj;
    hA[hi] = hb;
    size_t hi2 = ((size_t)(mh * sB + chl) * 4 + w) * 512 + lane2 * 8 + jj;
    hB[hi2] = hb;
  }
}

// W3 GEMM + relu -> plain bf16 [128,1920]. grid(30 nb, 2 mh) x 256 (4-wave K-split).
__global__ __launch_bounds__(256, 1) void k_w3(const u16* __restrict__ A2,
                                               const u16* __restrict__ W3r,
                                               const float* __restrict__ b3,
                                               u16* __restrict__ X3b) {
  __shared__ float red[4][4][16][64];
  const int tid = threadIdx.x;
  const int w = tid >> 6;
  const int lane = tid & 63;
  const int ln = lane & 15, quad = lane >> 4;
  const int nb = blockIdx.x;
  const int mh = blockIdx.y;
  const int lane_off = lane * 16;

  const char* aw = (const char*)A2 + ((size_t)mh * 60 + 15 * w) * 4096;
  const char* bw = (const char*)W3r + ((size_t)nb * 60 + 15 * w) * 4096;

  f32x4 acc[4][4] = {};
  gemm_pipe<15>(aw, bw, lane_off, acc);

#pragma unroll
  for (int mt = 0; mt < 4; ++mt)
#pragma unroll
    for (int nt = 0; nt < 4; ++nt)
      *(f32x4*)&red[w][nt][ln][mt * 16 + quad * 4] = acc[mt][nt];
  __syncthreads();

#pragma unroll
  for (int nt = 0; nt < 4; ++nt) {
    f32x4 s = *(const f32x4*)&red[0][nt][ln][w * 16 + quad * 4];
#pragma unroll
    for (int p = 1; p < 4; ++p) {
      f32x4 tv = *(const f32x4*)&red[p][nt][ln][w * 16 + quad * 4];
      s[0] += tv[0]; s[1] += tv[1]; s[2] += tv[2]; s[3] += tv[3];
    }
    int n = nb * 64 + nt * 16 + ln;
    float bias = b3[n];
#pragma unroll
    for (int r = 0; r < 4; ++r) {
      int m = mh * 64 + w * 16 + quad * 4 + r;
      X3b[(size_t)m * 1920 + n] = f2bf(fmaxf(s[r] + bias, 0.f));
    }
  }
}

// FUSED: W4 projection + output for step t (part A, = old k_w4out unit
// (m, pb=q)) THEN the per-atom MLP for step t+1, atoms a=2q and 2q+1
// (part B, = old k_mlp). The 8 projection outputs p in [8q,8q+8) are exactly
// ins[a=2q][0..3] ++ ins[a=2q+1][0..3] -- handed over in LDS, eliminating the
// prevb global round-trip AND one launch per step (5 -> 4 graph nodes/step).
// grid 1920 (m=bid/15, q=bid%15) x 64 threads.
__global__ __launch_bounds__(64) void k_w4mlp(
    const u16* __restrict__ x3, const float* __restrict__ W4,
    const float* __restrict__ b4, float* __restrict__ insb,
    const float* __restrict__ inputs, const int* __restrict__ burn,
    const float* __restrict__ W1, const float* __restrict__ b1,
    const float* __restrict__ W2, const float* __restrict__ b2,
    u16* __restrict__ A0, float* __restrict__ outp, int t) {
  __shared__ float h1s[64];
  __shared__ float insv[8];
  const int m = blockIdx.x / 15;
  const int q = blockIdx.x % 15;
  const int lane = threadIdx.x;

  // ---- part A: W4 dot + bias + residual, step t (verbatim w4out math) ----
  const u16* xr = x3 + (size_t)m * 1920;
  float xv[30];
#pragma unroll
  for (int i = 0; i < 30; ++i) xv[i] = bf2f(xr[lane + 64 * i]);
  float vout = 0.f;
#pragma unroll 1
  for (int pi = 0; pi < 8; ++pi) {
    int pp = q * 8 + pi;
    const float* wr = W4 + (size_t)pp * 1920;
    float s = 0.f;
#pragma unroll
    for (int i = 0; i < 30; ++i) s += xv[i] * wr[lane + 64 * i];
#pragma unroll
    for (int off = 32; off > 0; off >>= 1) s += __shfl_xor(s, off);
    if (lane == pi) vout = s + b4[pp] + insb[(size_t)m * 120 + pp];
  }
  if (lane < 8) {
    int pp = q * 8 + lane;
    outp[(((size_t)m * 30 + (pp >> 2)) * 64 + t) * 4 + (pp & 3)] = vout;
    insv[lane] = vout;          // hand to part B
  }
  __syncthreads();              // insv ready; part-A insb reads done

  // ---- part B: ins-select + MLP for step t+1 (verbatim k_mlp math) ----
  const bool gt = (t + 1 <= *burn);
  const int j = lane;
#pragma unroll 1
  for (int ai = 0; ai < 2; ++ai) {
    const int a = 2 * q + ai;
    const int ba = m * 30 + a;
    float i0, i1, i2, i3;
    if (gt) {
      const float* src = inputs + ((size_t)ba * 65 + (t + 1)) * 4;
      i0 = src[0]; i1 = src[1]; i2 = src[2]; i3 = src[3];
    } else {
      i0 = insv[ai * 4 + 0]; i1 = insv[ai * 4 + 1];
      i2 = insv[ai * 4 + 2]; i3 = insv[ai * 4 + 3];
    }
    float h1 = b1[j] + i0 * W1[j * 4 + 0] + i1 * W1[j * 4 + 1] +
               i2 * W1[j * 4 + 2] + i3 * W1[j * 4 + 3];
    h1 = fmaxf(h1, 0.f);
    h1s[j] = h1;
    __syncthreads();
    float h2 = b2[j];
    const float* w2r = W2 + j * 64;
#pragma unroll 8
    for (int k = 0; k < 64; ++k) h2 += h1s[k] * w2r[k];
    h2 = fmaxf(h2, 0.f);
    int mh = m >> 6, mloc = m & 63, mt = mloc >> 4, ln2 = mloc & 15;
    int ch = a * 2 + (j >> 5), quad2 = (j >> 3) & 3, jj = j & 7;
    size_t xi = ((size_t)(mh * 180 + ch) * 4 + mt) * 512 + (quad2 * 16 + ln2) * 8 + jj;
    A0[xi] = f2bf(h2);
    if (j < 4) {
      float iv = (j == 0) ? i0 : (j == 1) ? i1 : (j == 2) ? i2 : i3;
      insb[(size_t)ba * 4 + j] = iv;   // block-exclusive slots; post-sync
    }
    __syncthreads();            // h1s safe for next ai
  }
}

extern "C" void kernel_launch(void* const* d_in, const int* in_sizes, int n_in,
                              void* d_out, int out_size, void* d_ws, size_t ws_size,
                              hipStream_t stream) {
  (void)in_sizes; (void)n_in; (void)out_size;
  const float* inputs = (const float*)d_in[0];
  const float* W1 = (const float*)d_in[1];
  const float* b1 = (const float*)d_in[2];
  const float* W2 = (const float*)d_in[3];
  const float* b2 = (const float*)d_in[4];
  const float* Wih = (const float*)d_in[5];
  const float* Whh = (const float*)d_in[6];
  const float* bih = (const float*)d_in[7];
  const float* bhh = (const float*)d_in[8];
  const float* W3 = (const float*)d_in[9];
  const float* b3 = (const float*)d_in[10];
  const float* W4 = (const float*)d_in[11];
  const float* b4 = (const float*)d_in[12];
  const int* burn = (const int*)d_in[14];
  float* outp = (float*)d_out;
  char* ws = (char*)d_ws;

  // ---- workspace layout (bytes) ----
  float* cbuf = (float*)ws;                          // [2][128][1920] f32
  u16* A0 = (u16*)(ws + 1966080);                    // [2mh][180ch][4][512] u16
  u16* A1 = (u16*)(ws + 3440640);
  u16* A2 = (u16*)(ws + 4915200);                    // [2mh][60ch][4][512] u16
  u16* X3b = (u16*)(ws + 5406720);                   // [128][1920] bf16
  float* insb = (float*)(ws + 5898240);              // [128][120]
  float* prevb = (float*)(ws + 5959680);             // [128][120] (t=0 only)
  u16* Brep = (u16*)(ws + 6021120);                  // 58982400 u16
  u16* W3r = (u16*)(ws + 123985920);                 // 3686400 u16
  if (ws_size < 131358720) return;                   // insufficient scratch

  // zero c + A0 + A1 (1228800 floats)
  hipLaunchKernelGGL(k_zero, dim3(4800), dim3(256), 0, stream, (float*)ws);
  // repack weights to bf16 fragment-tiled
  hipLaunchKernelGGL(k_repB, dim3(28800), dim3(256), 0, stream, Wih, Whh, Brep);
  hipLaunchKernelGGL(k_repW3, dim3(1800), dim3(256), 0, stream, W3, W3r);

  const size_t BrepL = (size_t)120 * 120 * 2048;     // per-layer elements

  // t=0 MLP (burn-in => ground-truth inputs; prevb unused)
  hipLaunchKernelGGL(k_mlp, dim3(3840), dim3(64), 0, stream,
                     inputs, prevb, burn, W1, b1, W2, b2, A0, insb, 0);

  for (int t = 0; t < 64; ++t) {
    int p = t & 1;
    int rd_off = 60 + p * 60;          // h chunks read this step
    int wr_off = 60 + (1 - p) * 60;    // h chunks written this step

    // layer 0: A=A0, writes h0 -> A0 h-part(wr) and A1 x-part (stride 180)
    hipLaunchKernelGGL(k_gates, dim3(120, 2), dim3(256), 0, stream,
                       A0, Brep, bih, bhh, cbuf,
                       A0 + (size_t)wr_off * 2048, A1, rd_off, 180);
    // layer 1: A=A1, writes h1 -> A1 h-part(wr) and A2 (stride 60)
    hipLaunchKernelGGL(k_gates, dim3(120, 2), dim3(256), 0, stream,
                       A1, Brep + BrepL, bih + 7680, bhh + 7680, cbuf + 245760,
                       A1 + (size_t)wr_off * 2048, A2, rd_off, 60);
    hipLaunchKernelGGL(k_w3, dim3(30, 2), dim3(256), 0, stream, A2, W3r, b3, X3b);
    // fused: output step t + MLP for step t+1 (t=63's part B is dead work)
    hipLaunchKernelGGL(k_w4mlp, dim3(1920), dim3(64), 0, stream,
                       X3b, W4, b4, insb, inputs, burn, W1, b1, W2, b2,
                       A0, outp, t);
  }
}

// Round 14
// 5481.519 us; speedup vs baseline: 4.6035x; 1.0898x over previous
//
#include <hip/hip_runtime.h>
#include <stdint.h>

typedef unsigned short u16;
typedef __attribute__((ext_vector_type(8))) short bf16x8;
typedef __attribute__((ext_vector_type(4))) float f32x4;
typedef __attribute__((ext_vector_type(4))) u16 u16x4;

__device__ __forceinline__ u16 f2bf(float f) {
  union { float f; uint32_t u; } v; v.f = f;
  uint32_t u = v.u;
  uint32_t r = u + 0x7fffu + ((u >> 16) & 1u);
  return (u16)(r >> 16);
}
__device__ __forceinline__ float bf2f(u16 h) {
  union { uint32_t u; float f; } v; v.u = ((uint32_t)h) << 16; return v.f;
}
__device__ __forceinline__ float sigm(float x) { return 1.f / (1.f + __expf(-x)); }
__device__ __forceinline__ float tanhfast(float x) {
  float t = __expf(-2.f * fabsf(x));
  float r = (1.f - t) / (1.f + t);
  return x < 0.f ? -r : r;
}

__global__ __launch_bounds__(256) void k_zero(float* __restrict__ p) {
  p[(size_t)blockIdx.x * 256 + threadIdx.x] = 0.f;
}

// Repack Wih||Whh (fp32) -> bf16 fragment-tiled: [l][jb(120)][k0(120)][g(4)][lane(64)][8]
__global__ __launch_bounds__(256) void k_repB(const float* __restrict__ Wih,
                                              const float* __restrict__ Whh,
                                              u16* __restrict__ dst) {
  int e8 = blockIdx.x * 256 + threadIdx.x;
  if (e8 >= 7372800) return;
  int lane = e8 & 63;
  int t1 = e8 >> 6;
  int g = t1 & 3;
  int t2 = t1 >> 2;
  int k0 = t2 % 120;
  int t3 = t2 / 120;
  int jb = t3 % 120;
  int l = t3 / 120;
  int ln = lane & 15, quad = lane >> 4;
  int n = g * 1920 + jb * 16 + ln;
  const float* src = (k0 < 60)
      ? (Wih + ((size_t)(l * 7680 + n)) * 1920 + k0 * 32 + quad * 8)
      : (Whh + ((size_t)(l * 7680 + n)) * 1920 + (k0 - 60) * 32 + quad * 8);
  float4 a = ((const float4*)src)[0];
  float4 b = ((const float4*)src)[1];
  u16x4 o0, o1;
  o0[0] = f2bf(a.x); o0[1] = f2bf(a.y); o0[2] = f2bf(a.z); o0[3] = f2bf(a.w);
  o1[0] = f2bf(b.x); o1[1] = f2bf(b.y); o1[2] = f2bf(b.z); o1[3] = f2bf(b.w);
  ((u16x4*)(dst + (size_t)e8 * 8))[0] = o0;
  ((u16x4*)(dst + (size_t)e8 * 8))[1] = o1;
}

// Repack W3 (fp32 [1920,1920]) -> [nb(30)][k0(60)][nt(4)][lane(64)][8]
__global__ __launch_bounds__(256) void k_repW3(const float* __restrict__ W3,
                                               u16* __restrict__ dst) {
  int e8 = blockIdx.x * 256 + threadIdx.x;
  if (e8 >= 460800) return;
  int lane = e8 & 63;
  int t1 = e8 >> 6;
  int nt = t1 & 3;
  int t2 = t1 >> 2;
  int k0 = t2 % 60;
  int nb = t2 / 60;
  int ln = lane & 15, quad = lane >> 4;
  int n = nb * 64 + nt * 16 + ln;
  const float* src = W3 + (size_t)n * 1920 + k0 * 32 + quad * 8;
  float4 a = ((const float4*)src)[0];
  float4 b = ((const float4*)src)[1];
  u16x4 o0, o1;
  o0[0] = f2bf(a.x); o0[1] = f2bf(a.y); o0[2] = f2bf(a.z); o0[3] = f2bf(a.w);
  o1[0] = f2bf(b.x); o1[1] = f2bf(b.y); o1[2] = f2bf(b.z); o1[3] = f2bf(b.w);
  ((u16x4*)(dst + (size_t)e8 * 8))[0] = o0;
  ((u16x4*)(dst + (size_t)e8 * 8))[1] = o1;
}

// ins-select + per-atom MLP; writes X into A0 x-part (fragment-tiled) and insb
// (used ONCE, at t=0 -- later steps fuse this into k_w4mlp)
__global__ __launch_bounds__(64) void k_mlp(
    const float* __restrict__ inputs, const float* __restrict__ prevb,
    const int* __restrict__ burn,
    const float* __restrict__ W1, const float* __restrict__ b1,
    const float* __restrict__ W2, const float* __restrict__ b2,
    u16* __restrict__ A0, float* __restrict__ insb, int t) {
  __shared__ float h1s[64];
  int ba = blockIdx.x;              // b*30 + a
  int b = ba / 30, a = ba % 30;
  int j = threadIdx.x;
  bool gt = (t <= *burn);
  const float* src = gt ? (inputs + (((size_t)ba) * 65 + t) * 4)
                        : (prevb + (size_t)ba * 4);
  float i0 = src[0], i1 = src[1], i2 = src[2], i3 = src[3];
  float h1 = b1[j] + i0 * W1[j * 4 + 0] + i1 * W1[j * 4 + 1] +
             i2 * W1[j * 4 + 2] + i3 * W1[j * 4 + 3];
  h1 = fmaxf(h1, 0.f);
  h1s[j] = h1;
  __syncthreads();
  float h2 = b2[j];
  const float* w2r = W2 + j * 64;
#pragma unroll 8
  for (int k = 0; k < 64; ++k) h2 += h1s[k] * w2r[k];
  h2 = fmaxf(h2, 0.f);
  // tiled write: m=b, k=a*64+j
  int mh = b >> 6, mloc = b & 63, mt = mloc >> 4, ln2 = mloc & 15;
  int ch = a * 2 + (j >> 5), quad2 = (j >> 3) & 3, jj = j & 7;
  size_t xi = ((size_t)(mh * 180 + ch) * 4 + mt) * 512 + (quad2 * 16 + ln2) * 8 + jj;
  A0[xi] = f2bf(h2);
  if (j < 4) insb[(size_t)ba * 4 + j] = src[j];
}

// Rolling-pipeline fragment GEMM: ITERS k-iters (32 k each), depth 5.
template <int ITERS>
__device__ __forceinline__ void gemm_pipe(const char* __restrict__ aw,
                                          const char* __restrict__ bw,
                                          int lane_off, f32x4 acc[4][4]) {
  constexpr int D = 5;
  bf16x8 Af[D][4], Bf[D][4];
#pragma unroll
  for (int p = 0; p < D; ++p) {
#pragma unroll
    for (int mt = 0; mt < 4; ++mt)
      Af[p][mt] = *(const bf16x8*)(aw + p * 4096 + mt * 1024 + lane_off);
#pragma unroll
    for (int nt = 0; nt < 4; ++nt)
      Bf[p][nt] = *(const bf16x8*)(bw + p * 4096 + nt * 1024 + lane_off);
  }
  for (int o = 0; o < (ITERS - D) / D; ++o) {
    const char* ap = aw + (size_t)(o + 1) * (D * 4096);
    const char* bp = bw + (size_t)(o + 1) * (D * 4096);
#pragma unroll
    for (int d = 0; d < D; ++d) {
#pragma unroll
      for (int mt = 0; mt < 4; ++mt)
#pragma unroll
        for (int nt = 0; nt < 4; ++nt)
          acc[mt][nt] = __builtin_amdgcn_mfma_f32_16x16x32_bf16(
              Af[d][mt], Bf[d][nt], acc[mt][nt], 0, 0, 0);
#pragma unroll
      for (int mt = 0; mt < 4; ++mt)
        Af[d][mt] = *(const bf16x8*)(ap + d * 4096 + mt * 1024 + lane_off);
#pragma unroll
      for (int nt = 0; nt < 4; ++nt)
        Bf[d][nt] = *(const bf16x8*)(bp + d * 4096 + nt * 1024 + lane_off);
    }
  }
#pragma unroll
  for (int d = 0; d < D; ++d) {
#pragma unroll
    for (int mt = 0; mt < 4; ++mt)
#pragma unroll
      for (int nt = 0; nt < 4; ++nt)
        acc[mt][nt] = __builtin_amdgcn_mfma_f32_16x16x32_bf16(
            Af[d][mt], Bf[d][nt], acc[mt][nt], 0, 0, 0);
  }
}

// Dual-M rolling-pipeline GEMM: ONE B-fragment load feeds BOTH mh halves
// (32 MFMA per k-iter). Depth D=3 to fit registers (~300 VGPR:
// 144 frag + 128 acc). B traffic per k_gates launch: 113 -> 57 MB.
template <int ITERS, int D>
__device__ __forceinline__ void gemm_pipe2(const char* __restrict__ a0,
                                           const char* __restrict__ a1,
                                           const char* __restrict__ bw,
                                           int lane_off,
                                           f32x4 acc0[4][4], f32x4 acc1[4][4]) {
  static_assert((ITERS - D) % D == 0, "pipeline depth");
  bf16x8 A0f[D][4], A1f[D][4], Bf[D][4];
#pragma unroll
  for (int p = 0; p < D; ++p) {
#pragma unroll
    for (int mt = 0; mt < 4; ++mt) {
      A0f[p][mt] = *(const bf16x8*)(a0 + p * 4096 + mt * 1024 + lane_off);
      A1f[p][mt] = *(const bf16x8*)(a1 + p * 4096 + mt * 1024 + lane_off);
    }
#pragma unroll
    for (int nt = 0; nt < 4; ++nt)
      Bf[p][nt] = *(const bf16x8*)(bw + p * 4096 + nt * 1024 + lane_off);
  }
  for (int o = 0; o < (ITERS - D) / D; ++o) {
    const char* ap0 = a0 + (size_t)(o + 1) * (D * 4096);
    const char* ap1 = a1 + (size_t)(o + 1) * (D * 4096);
    const char* bp = bw + (size_t)(o + 1) * (D * 4096);
#pragma unroll
    for (int d = 0; d < D; ++d) {
#pragma unroll
      for (int mt = 0; mt < 4; ++mt)
#pragma unroll
        for (int nt = 0; nt < 4; ++nt) {
          acc0[mt][nt] = __builtin_amdgcn_mfma_f32_16x16x32_bf16(
              A0f[d][mt], Bf[d][nt], acc0[mt][nt], 0, 0, 0);
          acc1[mt][nt] = __builtin_amdgcn_mfma_f32_16x16x32_bf16(
              A1f[d][mt], Bf[d][nt], acc1[mt][nt], 0, 0, 0);
        }
#pragma unroll
      for (int mt = 0; mt < 4; ++mt) {
        A0f[d][mt] = *(const bf16x8*)(ap0 + d * 4096 + mt * 1024 + lane_off);
        A1f[d][mt] = *(const bf16x8*)(ap1 + d * 4096 + mt * 1024 + lane_off);
      }
#pragma unroll
      for (int nt = 0; nt < 4; ++nt)
        Bf[d][nt] = *(const bf16x8*)(bp + d * 4096 + nt * 1024 + lane_off);
    }
  }
#pragma unroll
  for (int d = 0; d < D; ++d) {
#pragma unroll
    for (int mt = 0; mt < 4; ++mt)
#pragma unroll
      for (int nt = 0; nt < 4; ++nt) {
        acc0[mt][nt] = __builtin_amdgcn_mfma_f32_16x16x32_bf16(
            A0f[d][mt], Bf[d][nt], acc0[mt][nt], 0, 0, 0);
        acc1[mt][nt] = __builtin_amdgcn_mfma_f32_16x16x32_bf16(
            A1f[d][mt], Bf[d][nt], acc1[mt][nt], 0, 0, 0);
      }
  }
}

// Gates GEMM + fused LSTM cell, BOTH batch halves per block.
// grid(120 jb) x 256 threads (4 waves, K-split). Each B fragment is loaded
// once and used for mh=0 and mh=1 (per-acc accumulation order identical to
// the old per-mh kernel -> bitwise-identical results).
__global__ __launch_bounds__(256, 1) void k_gates2(
    const u16* __restrict__ Atl, const u16* __restrict__ Brep_l,
    const float* __restrict__ bih_l, const float* __restrict__ bhh_l,
    float* __restrict__ c_l, u16* __restrict__ hA, u16* __restrict__ hB,
    int rd_off, int sB) {
  __shared__ float red[4][4][16][128];   // [p][nt][ln][m_local] = 128 KB
  const int tid = threadIdx.x;
  const int w = tid >> 6;
  const int lane = tid & 63;
  const int ln = lane & 15, quad = lane >> 4;
  const int jb = blockIdx.x;
  const int lane_off = lane * 16;

  const size_t choff = (w < 2) ? (size_t)(30 * w) * 4096
                               : ((size_t)rd_off + 30 * (w - 2)) * 4096;
  const char* a0 = (const char*)Atl + choff;                        // mh=0
  const char* a1 = (const char*)Atl + (size_t)180 * 4096 + choff;   // mh=1
  const char* bw = (const char*)Brep_l + ((size_t)jb * 120 + 30 * w) * 4096;

  f32x4 acc0[4][4] = {}, acc1[4][4] = {};
  gemm_pipe2<30, 3>(a0, a1, bw, lane_off, acc0, acc1);

#pragma unroll
  for (int mt = 0; mt < 4; ++mt)
#pragma unroll
    for (int nt = 0; nt < 4; ++nt) {
      *(f32x4*)&red[w][nt][ln][mt * 16 + quad * 4] = acc0[mt][nt];
      *(f32x4*)&red[w][nt][ln][64 + mt * 16 + quad * 4] = acc1[mt][nt];
    }
  __syncthreads();

  const int kh = jb * 16 + ln;                 // hidden index j
  const int chl = kh >> 5, quad2 = (kh >> 3) & 3, jj = kh & 7;
  float bs[4];
#pragma unroll
  for (int gi = 0; gi < 4; ++gi) bs[gi] = bih_l[gi * 1920 + kh] + bhh_l[gi * 1920 + kh];

#pragma unroll
  for (int mh = 0; mh < 2; ++mh) {
    f32x4 g[4];
#pragma unroll
    for (int nt = 0; nt < 4; ++nt) {
      f32x4 s = *(const f32x4*)&red[0][nt][ln][mh * 64 + w * 16 + quad * 4];
#pragma unroll
      for (int p = 1; p < 4; ++p) {
        f32x4 tv = *(const f32x4*)&red[p][nt][ln][mh * 64 + w * 16 + quad * 4];
        s[0] += tv[0]; s[1] += tv[1]; s[2] += tv[2]; s[3] += tv[3];
      }
      g[nt] = s;
    }
#pragma unroll
    for (int r = 0; r < 4; ++r) {
      int m = mh * 64 + w * 16 + quad * 4 + r;
      float vi = g[0][r] + bs[0];
      float vf = g[1][r] + bs[1];
      float vg = g[2][r] + bs[2];
      float vo = g[3][r] + bs[3];
      size_t ci = (size_t)m * 1920 + kh;
      float cn = sigm(vf) * c_l[ci] + sigm(vi) * tanhfast(vg);
      float hn = sigm(vo) * tanhfast(cn);
      c_l[ci] = cn;
      u16 hb = f2bf(hn);
      int lane2 = quad2 * 16 + quad * 4 + r;
      size_t hi = ((size_t)(mh * 180 + chl) * 4 + w) * 512 + lane2 * 8 + jj;
      hA[hi] = hb;
      size_t hi2 = ((size_t)(mh * sB + chl) * 4 + w) * 512 + lane2 * 8 + jj;
      hB[hi2] = hb;
    }
  }
}

// W3 GEMM + relu -> plain bf16 [128,1920]. grid(30 nb, 2 mh) x 256 (4-wave K-split).
__global__ __launch_bounds__(256, 1) void k_w3(const u16* __restrict__ A2,
                                               const u16* __restrict__ W3r,
                                               const float* __restrict__ b3,
                                               u16* __restrict__ X3b) {
  __shared__ float red[4][4][16][64];
  const int tid = threadIdx.x;
  const int w = tid >> 6;
  const int lane = tid & 63;
  const int ln = lane & 15, quad = lane >> 4;
  const int nb = blockIdx.x;
  const int mh = blockIdx.y;
  const int lane_off = lane * 16;

  const char* aw = (const char*)A2 + ((size_t)mh * 60 + 15 * w) * 4096;
  const char* bw = (const char*)W3r + ((size_t)nb * 60 + 15 * w) * 4096;

  f32x4 acc[4][4] = {};
  gemm_pipe<15>(aw, bw, lane_off, acc);

#pragma unroll
  for (int mt = 0; mt < 4; ++mt)
#pragma unroll
    for (int nt = 0; nt < 4; ++nt)
      *(f32x4*)&red[w][nt][ln][mt * 16 + quad * 4] = acc[mt][nt];
  __syncthreads();

#pragma unroll
  for (int nt = 0; nt < 4; ++nt) {
    f32x4 s = *(const f32x4*)&red[0][nt][ln][w * 16 + quad * 4];
#pragma unroll
    for (int p = 1; p < 4; ++p) {
      f32x4 tv = *(const f32x4*)&red[p][nt][ln][w * 16 + quad * 4];
      s[0] += tv[0]; s[1] += tv[1]; s[2] += tv[2]; s[3] += tv[3];
    }
    int n = nb * 64 + nt * 16 + ln;
    float bias = b3[n];
#pragma unroll
    for (int r = 0; r < 4; ++r) {
      int m = mh * 64 + w * 16 + quad * 4 + r;
      X3b[(size_t)m * 1920 + n] = f2bf(fmaxf(s[r] + bias, 0.f));
    }
  }
}

// FUSED: W4 projection + output for step t (part A) THEN the per-atom MLP for
// step t+1, atoms a=2q and 2q+1 (part B). grid 1920 (m=bid/15, q=bid%15) x 64.
__global__ __launch_bounds__(64) void k_w4mlp(
    const u16* __restrict__ x3, const float* __restrict__ W4,
    const float* __restrict__ b4, float* __restrict__ insb,
    const float* __restrict__ inputs, const int* __restrict__ burn,
    const float* __restrict__ W1, const float* __restrict__ b1,
    const float* __restrict__ W2, const float* __restrict__ b2,
    u16* __restrict__ A0, float* __restrict__ outp, int t) {
  __shared__ float h1s[64];
  __shared__ float insv[8];
  const int m = blockIdx.x / 15;
  const int q = blockIdx.x % 15;
  const int lane = threadIdx.x;

  // ---- part A: W4 dot + bias + residual, step t (verbatim w4out math) ----
  const u16* xr = x3 + (size_t)m * 1920;
  float xv[30];
#pragma unroll
  for (int i = 0; i < 30; ++i) xv[i] = bf2f(xr[lane + 64 * i]);
  float vout = 0.f;
#pragma unroll 1
  for (int pi = 0; pi < 8; ++pi) {
    int pp = q * 8 + pi;
    const float* wr = W4 + (size_t)pp * 1920;
    float s = 0.f;
#pragma unroll
    for (int i = 0; i < 30; ++i) s += xv[i] * wr[lane + 64 * i];
#pragma unroll
    for (int off = 32; off > 0; off >>= 1) s += __shfl_xor(s, off);
    if (lane == pi) vout = s + b4[pp] + insb[(size_t)m * 120 + pp];
  }
  if (lane < 8) {
    int pp = q * 8 + lane;
    outp[(((size_t)m * 30 + (pp >> 2)) * 64 + t) * 4 + (pp & 3)] = vout;
    insv[lane] = vout;          // hand to part B
  }
  __syncthreads();              // insv ready; part-A insb reads done

  // ---- part B: ins-select + MLP for step t+1 (verbatim k_mlp math) ----
  const bool gt = (t + 1 <= *burn);
  const int j = lane;
#pragma unroll 1
  for (int ai = 0; ai < 2; ++ai) {
    const int a = 2 * q + ai;
    const int ba = m * 30 + a;
    float i0, i1, i2, i3;
    if (gt) {
      const float* src = inputs + ((size_t)ba * 65 + (t + 1)) * 4;
      i0 = src[0]; i1 = src[1]; i2 = src[2]; i3 = src[3];
    } else {
      i0 = insv[ai * 4 + 0]; i1 = insv[ai * 4 + 1];
      i2 = insv[ai * 4 + 2]; i3 = insv[ai * 4 + 3];
    }
    float h1 = b1[j] + i0 * W1[j * 4 + 0] + i1 * W1[j * 4 + 1] +
               i2 * W1[j * 4 + 2] + i3 * W1[j * 4 + 3];
    h1 = fmaxf(h1, 0.f);
    h1s[j] = h1;
    __syncthreads();
    float h2 = b2[j];
    const float* w2r = W2 + j * 64;
#pragma unroll 8
    for (int k = 0; k < 64; ++k) h2 += h1s[k] * w2r[k];
    h2 = fmaxf(h2, 0.f);
    int mh = m >> 6, mloc = m & 63, mt = mloc >> 4, ln2 = mloc & 15;
    int ch = a * 2 + (j >> 5), quad2 = (j >> 3) & 3, jj = j & 7;
    size_t xi = ((size_t)(mh * 180 + ch) * 4 + mt) * 512 + (quad2 * 16 + ln2) * 8 + jj;
    A0[xi] = f2bf(h2);
    if (j < 4) {
      float iv = (j == 0) ? i0 : (j == 1) ? i1 : (j == 2) ? i2 : i3;
      insb[(size_t)ba * 4 + j] = iv;   // block-exclusive slots; post-sync
    }
    __syncthreads();            // h1s safe for next ai
  }
}

extern "C" void kernel_launch(void* const* d_in, const int* in_sizes, int n_in,
                              void* d_out, int out_size, void* d_ws, size_t ws_size,
                              hipStream_t stream) {
  (void)in_sizes; (void)n_in; (void)out_size;
  const float* inputs = (const float*)d_in[0];
  const float* W1 = (const float*)d_in[1];
  const float* b1 = (const float*)d_in[2];
  const float* W2 = (const float*)d_in[3];
  const float* b2 = (const float*)d_in[4];
  const float* Wih = (const float*)d_in[5];
  const float* Whh = (const float*)d_in[6];
  const float* bih = (const float*)d_in[7];
  const float* bhh = (const float*)d_in[8];
  const float* W3 = (const float*)d_in[9];
  const float* b3 = (const float*)d_in[10];
  const float* W4 = (const float*)d_in[11];
  const float* b4 = (const float*)d_in[12];
  const int* burn = (const int*)d_in[14];
  float* outp = (float*)d_out;
  char* ws = (char*)d_ws;

  // ---- workspace layout (bytes) ----
  float* cbuf = (float*)ws;                          // [2][128][1920] f32
  u16* A0 = (u16*)(ws + 1966080);                    // [2mh][180ch][4][512] u16
  u16* A1 = (u16*)(ws + 3440640);
  u16* A2 = (u16*)(ws + 4915200);                    // [2mh][60ch][4][512] u16
  u16* X3b = (u16*)(ws + 5406720);                   // [128][1920] bf16
  float* insb = (float*)(ws + 5898240);              // [128][120]
  float* prevb = (float*)(ws + 5959680);             // [128][120] (t=0 only)
  u16* Brep = (u16*)(ws + 6021120);                  // 58982400 u16
  u16* W3r = (u16*)(ws + 123985920);                 // 3686400 u16
  if (ws_size < 131358720) return;                   // insufficient scratch

  // zero c + A0 + A1 (1228800 floats)
  hipLaunchKernelGGL(k_zero, dim3(4800), dim3(256), 0, stream, (float*)ws);
  // repack weights to bf16 fragment-tiled
  hipLaunchKernelGGL(k_repB, dim3(28800), dim3(256), 0, stream, Wih, Whh, Brep);
  hipLaunchKernelGGL(k_repW3, dim3(1800), dim3(256), 0, stream, W3, W3r);

  const size_t BrepL = (size_t)120 * 120 * 2048;     // per-layer elements

  // t=0 MLP (burn-in => ground-truth inputs; prevb unused)
  hipLaunchKernelGGL(k_mlp, dim3(3840), dim3(64), 0, stream,
                     inputs, prevb, burn, W1, b1, W2, b2, A0, insb, 0);

  for (int t = 0; t < 64; ++t) {
    int p = t & 1;
    int rd_off = 60 + p * 60;          // h chunks read this step
    int wr_off = 60 + (1 - p) * 60;    // h chunks written this step

    // layer 0: A=A0 (both mh), writes h0 -> A0 h-part(wr) and A1 x-part
    hipLaunchKernelGGL(k_gates2, dim3(120), dim3(256), 0, stream,
                       A0, Brep, bih, bhh, cbuf,
                       A0 + (size_t)wr_off * 2048, A1, rd_off, 180);
    // layer 1: A=A1 (both mh), writes h1 -> A1 h-part(wr) and A2
    hipLaunchKernelGGL(k_gates2, dim3(120), dim3(256), 0, stream,
                       A1, Brep + BrepL, bih + 7680, bhh + 7680, cbuf + 245760,
                       A1 + (size_t)wr_off * 2048, A2, rd_off, 60);
    hipLaunchKernelGGL(k_w3, dim3(30, 2), dim3(256), 0, stream, A2, W3r, b3, X3b);
    // fused: output step t + MLP for step t+1 (t=63's part B is dead work)
    hipLaunchKernelGGL(k_w4mlp, dim3(1920), dim3(64), 0, stream,
                       X3b, W4, b4, insb, inputs, burn, W1, b1, W2, b2,
                       A0, outp, t);
  }
}